// Round 1
// baseline (659.607 us; speedup 1.0000x reference)
//
#include <hip/hip_runtime.h>
#include <hip/hip_bf16.h>

// Problem constants
#define NTOK 8192
#define SEQ 64
#define EMBD 512
#define NEXP 16
#define FFND 2048
#define CAPS 512

typedef __attribute__((ext_vector_type(8))) short short8;
typedef __attribute__((ext_vector_type(4))) float f32x4;

__device__ __forceinline__ unsigned short f2bf(float f) {
  union { float f; unsigned u; } a; a.f = f;
  unsigned r = (a.u + 0x7fff + ((a.u >> 16) & 1)) >> 16;  // RNE
  return (unsigned short)r;
}

// ---------------- transpose + fp32->bf16 convert:  in [E][R][C] f32 -> out [E][C][R] bf16
__global__ void transpose_bf16(const float* __restrict__ in, unsigned short* __restrict__ out,
                               int R, int C) {
  __shared__ float tile[32][33];
  int e = blockIdx.z;
  int c0 = blockIdx.x * 32, r0 = blockIdx.y * 32;
  const float* ip = in + (size_t)e * R * C;
  unsigned short* op = out + (size_t)e * R * C;
  int tx = threadIdx.x, ty = threadIdx.y;  // 32 x 8
  #pragma unroll
  for (int i = 0; i < 32; i += 8)
    tile[ty + i][tx] = ip[(size_t)(r0 + ty + i) * C + c0 + tx];
  __syncthreads();
  #pragma unroll
  for (int i = 0; i < 32; i += 8)
    op[(size_t)(c0 + ty + i) * R + r0 + tx] = f2bf(tile[tx][ty + i]);
}

// ---------------- embedding mean-pool: xm[b][:] = mean_s emb[x[b][s]][:]
__global__ void pool_kernel(const int* __restrict__ x, const float* __restrict__ emb,
                            float* __restrict__ xm, unsigned short* __restrict__ xmb) {
  __shared__ int sx[SEQ];
  int b = blockIdx.x, tid = threadIdx.x;  // 128 threads, 4 floats each
  if (tid < SEQ) sx[tid] = x[b * SEQ + tid];
  __syncthreads();
  float ax = 0, ay = 0, az = 0, aw = 0;
  const float4* eb = (const float4*)emb;
  #pragma unroll 8
  for (int s = 0; s < SEQ; s++) {
    float4 v = eb[(size_t)sx[s] * (EMBD / 4) + tid];
    ax += v.x; ay += v.y; az += v.z; aw += v.w;
  }
  const float sc = 1.0f / 64.0f;
  ax *= sc; ay *= sc; az *= sc; aw *= sc;
  float4 o = {ax, ay, az, aw};
  ((float4*)(xm + (size_t)b * EMBD))[tid] = o;
  ushort4 u = {f2bf(ax), f2bf(ay), f2bf(az), f2bf(aw)};
  ((ushort4*)(xmb + (size_t)b * EMBD))[tid] = u;
}

// ---------------- gate: logits = xm @ wg, softmax, argmax (fp32, match ref ordering)
__global__ void gate_kernel(const float* __restrict__ xm, const float* __restrict__ wg,
                            int* __restrict__ eidx, float* __restrict__ gate) {
  __shared__ float xs[EMBD];
  int b = blockIdx.x, tid = threadIdx.x;  // 64 threads
  ((float4*)xs)[tid] = ((const float4*)(xm + (size_t)b * EMBD))[tid];
  ((float4*)xs)[tid + 64] = ((const float4*)(xm + (size_t)b * EMBD))[tid + 64];
  __syncthreads();
  int e = tid & 15, q = tid >> 4;
  float acc = 0;
  for (int k = q * 128; k < q * 128 + 128; k++) acc += xs[k] * wg[k * NEXP + e];
  acc += __shfl_xor(acc, 16);
  acc += __shfl_xor(acc, 32);
  // all 64 lanes now hold logit of expert (tid&15)
  float best = acc; int bi = e;
  #pragma unroll
  for (int d = 1; d < 16; d <<= 1) {
    float ov = __shfl_xor(best, d); int oi = __shfl_xor(bi, d);
    if (ov > best || (ov == best && oi < bi)) { best = ov; bi = oi; }
  }
  float s = expf(acc - best);
  #pragma unroll
  for (int d = 1; d < 16; d <<= 1) s += __shfl_xor(s, d);
  if (tid == 0) { eidx[b] = bi; gate[b] = 1.0f / s; }  // softmax prob of argmax expert
}

// ---------------- slot assignment: sequential per-expert prefix count (order matters!)
__global__ void assign_kernel(const int* __restrict__ eidx, int* __restrict__ slot,
                              int* __restrict__ dest) {
  __shared__ int sidx[NTOK];
  int tid = threadIdx.x;  // 1024 = 16 waves
  for (int i = tid; i < NTOK; i += 1024) { sidx[i] = eidx[i]; dest[i] = 0; }
  __syncthreads();
  int e = tid >> 6;      // wave id == expert
  int lane = tid & 63;
  int run = 0;
  for (int c = 0; c < NTOK; c += 64) {
    int v = sidx[c + lane];
    unsigned long long m = __ballot(v == e);
    int before = __popcll(m & ((1ull << lane) - 1ull));
    if (v == e) {
      int sl = run + before;
      if (sl < CAPS) { slot[c + lane] = sl; dest[e * CAPS + sl] = c + lane; }
      else slot[c + lane] = -1;
    }
    run += __popcll(m);
  }
}

// ---------------- grouped GEMM (bf16 MFMA, 128x128 tile, 4 waves, XOR-swizzled LDS)
// C[m][n] = sum_k A[m][k] * BT[n][k]  (+bias[n]),  per expert e = blockIdx.z
template <int KTOT, int NTOTL, bool GATHER, bool RELU_BF16>
__global__ __launch_bounds__(256) void gemm_moe(
    const unsigned short* __restrict__ A0, const int* __restrict__ dest,
    const unsigned short* __restrict__ BT, const float* __restrict__ bias,
    unsigned short* __restrict__ hout, float* __restrict__ yout) {
  __shared__ unsigned short Als[128 * 64];
  __shared__ unsigned short Bls[128 * 64];
  __shared__ int tokrow[128];

  const int e = blockIdx.z;
  const int n0 = blockIdx.x * 128;
  const int m0 = blockIdx.y * 128;
  const int tid = threadIdx.x;
  const int lane = tid & 63;
  const int wv = tid >> 6;
  const int wr = (wv >> 1) * 64;
  const int wc = (wv & 1) * 64;
  const int l15 = lane & 15;
  const int lhi = lane >> 4;

  if (GATHER) {
    if (tid < 128) tokrow[tid] = dest[e * CAPS + m0 + tid];
  }
  __syncthreads();

  const int srow = tid >> 3;  // 0..31
  const int skc = tid & 7;    // 16B chunk within 64-elem k row

  const unsigned short* aptr[4];
  const unsigned short* bptr[4];
  #pragma unroll
  for (int i = 0; i < 4; i++) {
    int row = i * 32 + srow;
    if (GATHER) aptr[i] = A0 + (size_t)tokrow[row] * KTOT + skc * 8;
    else        aptr[i] = A0 + ((size_t)(e * CAPS + m0 + row)) * KTOT + skc * 8;
    bptr[i] = BT + ((size_t)e * NTOTL + n0 + row) * KTOT + skc * 8;
  }

  f32x4 acc[4][4];
  #pragma unroll
  for (int a = 0; a < 4; a++)
    #pragma unroll
    for (int b = 0; b < 4; b++) acc[a][b] = (f32x4){0.f, 0.f, 0.f, 0.f};

  float4 av[4], bv[4];
  auto loadAB = [&](int k0) {
    #pragma unroll
    for (int i = 0; i < 4; i++) {
      av[i] = *(const float4*)(aptr[i] + k0);
      bv[i] = *(const float4*)(bptr[i] + k0);
    }
  };
  auto storeLds = [&]() {
    #pragma unroll
    for (int i = 0; i < 4; i++) {
      int row = i * 32 + srow;
      int off = row * 128 + ((skc * 16) ^ ((row & 7) << 4));
      *(float4*)((char*)Als + off) = av[i];
      *(float4*)((char*)Bls + off) = bv[i];
    }
  };

  loadAB(0);
  const int NK = KTOT / 64;
  for (int kt = 0; kt < NK; kt++) {
    __syncthreads();
    storeLds();
    __syncthreads();
    if (kt + 1 < NK) loadAB((kt + 1) * 64);
    #pragma unroll
    for (int ks = 0; ks < 2; ks++) {
      short8 af[4], bfr[4];
      #pragma unroll
      for (int mi = 0; mi < 4; mi++) {
        int row = wr + mi * 16 + l15;
        int off = row * 128 + (((ks * 32 + lhi * 8) * 2) ^ ((row & 7) << 4));
        af[mi] = *(const short8*)((const char*)Als + off);
      }
      #pragma unroll
      for (int ni = 0; ni < 4; ni++) {
        int row = wc + ni * 16 + l15;
        int off = row * 128 + (((ks * 32 + lhi * 8) * 2) ^ ((row & 7) << 4));
        bfr[ni] = *(const short8*)((const char*)Bls + off);
      }
      #pragma unroll
      for (int mi = 0; mi < 4; mi++)
        #pragma unroll
        for (int ni = 0; ni < 4; ni++)
          acc[mi][ni] = __builtin_amdgcn_mfma_f32_16x16x32_bf16(af[mi], bfr[ni], acc[mi][ni], 0, 0, 0);
    }
  }

  // epilogue: D row=(lane>>4)*4+j, col=lane&15 (m89-verified)
  #pragma unroll
  for (int ni = 0; ni < 4; ni++) {
    int col = n0 + wc + ni * 16 + l15;
    float bs = bias[e * NTOTL + col];
    #pragma unroll
    for (int mi = 0; mi < 4; mi++) {
      f32x4 v = acc[mi][ni];
      #pragma unroll
      for (int j = 0; j < 4; j++) {
        int row = m0 + wr + mi * 16 + lhi * 4 + j;
        float xv = v[j] + bs;
        size_t oidx = ((size_t)(e * CAPS + row)) * NTOTL + col;
        if (RELU_BF16) hout[oidx] = f2bf(fmaxf(xv, 0.f));
        else           yout[oidx] = xv;
      }
    }
  }
}

// ---------------- combine + final fc + log_softmax (one wave per token)
__global__ void combine_kernel(const float* __restrict__ ye, const int* __restrict__ eidx,
                               const int* __restrict__ slot, const float* __restrict__ gate,
                               const float* __restrict__ fcw, const float* __restrict__ fcb,
                               float* __restrict__ out) {
  int b = blockIdx.x * 4 + (threadIdx.x >> 6);
  int lane = threadIdx.x & 63;
  int s = slot[b];
  float z0, z1;
  if (s >= 0) {
    const float* y = ye + ((size_t)(eidx[b] * CAPS + s)) * EMBD;
    float a0 = 0, a1 = 0;
    #pragma unroll
    for (int i = 0; i < EMBD / 64; i++) {
      int c = lane + i * 64;
      float v = y[c];
      a0 += v * fcw[c * 2 + 0];
      a1 += v * fcw[c * 2 + 1];
    }
    #pragma unroll
    for (int d = 1; d < 64; d <<= 1) { a0 += __shfl_xor(a0, d); a1 += __shfl_xor(a1, d); }
    float g = gate[b];
    z0 = g * a0 + fcb[0];
    z1 = g * a1 + fcb[1];
  } else {
    z0 = fcb[0]; z1 = fcb[1];  // dropped token: y = 0
  }
  if (lane == 0) {
    float m = fmaxf(z0, z1);
    float lse = m + logf(expf(z0 - m) + expf(z1 - m));
    out[(size_t)b * 2 + 0] = z0 - lse;
    out[(size_t)b * 2 + 1] = z1 - lse;
  }
}

extern "C" void kernel_launch(void* const* d_in, const int* in_sizes, int n_in,
                              void* d_out, int out_size, void* d_ws, size_t ws_size,
                              hipStream_t stream) {
  const int* x = (const int*)d_in[0];
  const float* emb = (const float*)d_in[1];
  const float* wg = (const float*)d_in[2];
  const float* w1 = (const float*)d_in[3];
  const float* b1 = (const float*)d_in[4];
  const float* w2 = (const float*)d_in[5];
  const float* b2 = (const float*)d_in[6];
  const float* fcw = (const float*)d_in[7];
  const float* fcb = (const float*)d_in[8];
  float* out = (float*)d_out;

  char* ws = (char*)d_ws;
  float* xm            = (float*)(ws + 0);                    // 16 MB
  unsigned short* xmb  = (unsigned short*)(ws + 16777216);    // 8 MB
  unsigned short* w1T  = (unsigned short*)(ws + 25165824);    // 32 MB  [E][FFN][EMB]
  unsigned short* w2T  = (unsigned short*)(ws + 58720256);    // 32 MB  [E][EMB][FFN]
  unsigned short* h    = (unsigned short*)(ws + 92274688);    // 32 MB  [E][CAP][FFN]
  float* ye            = (float*)(ws + 125829120);            // 16 MB  [E][CAP][EMB]
  int* eidx            = (int*)(ws + 142606336);
  float* gate          = (float*)(ws + 142639104);
  int* slot            = (int*)(ws + 142671872);
  int* dest            = (int*)(ws + 142704640);              // total ~136.2 MB

  // weights: transpose to n-major + convert to bf16
  transpose_bf16<<<dim3(FFND / 32, EMBD / 32, NEXP), dim3(32, 8), 0, stream>>>(w1, w1T, EMBD, FFND);
  transpose_bf16<<<dim3(EMBD / 32, FFND / 32, NEXP), dim3(32, 8), 0, stream>>>(w2, w2T, FFND, EMBD);
  pool_kernel<<<NTOK, 128, 0, stream>>>(x, emb, xm, xmb);
  gate_kernel<<<NTOK, 64, 0, stream>>>(xm, wg, eidx, gate);
  assign_kernel<<<1, 1024, 0, stream>>>(eidx, slot, dest);
  // FFN1: [CAP x EMB] @ [EMB x FFN] -> relu -> h (bf16)
  gemm_moe<EMBD, FFND, true, true><<<dim3(FFND / 128, CAPS / 128, NEXP), 256, 0, stream>>>(
      xmb, dest, w1T, b1, h, nullptr);
  // FFN2: [CAP x FFN] @ [FFN x EMB] -> ye (fp32)
  gemm_moe<FFND, EMBD, false, false><<<dim3(EMBD / 128, CAPS / 128, NEXP), 256, 0, stream>>>(
      h, nullptr, w2T, b2, nullptr, ye);
  combine_kernel<<<NTOK / 4, 256, 0, stream>>>(ye, eidx, slot, gate, fcw, fcb, out);
}

// Round 2
// 460.646 us; speedup vs baseline: 1.4319x; 1.4319x over previous
//
#include <hip/hip_runtime.h>
#include <hip/hip_bf16.h>

// Problem constants
#define NTOK 8192
#define SEQ 64
#define EMBD 512
#define NEXP 16
#define FFND 2048
#define CAPS 512

typedef __attribute__((ext_vector_type(8))) short short8;
typedef __attribute__((ext_vector_type(4))) float f32x4;

typedef const __attribute__((address_space(1))) unsigned int* as1_u32p;
typedef __attribute__((address_space(3))) unsigned int* as3_u32p;

__device__ __forceinline__ unsigned short f2bf(float f) {
  union { float f; unsigned u; } a; a.f = f;
  unsigned r = (a.u + 0x7fff + ((a.u >> 16) & 1)) >> 16;  // RNE
  return (unsigned short)r;
}
__device__ __forceinline__ float bf2f(unsigned short h) {
  union { unsigned u; float f; } a; a.u = ((unsigned)h) << 16; return a.f;
}

// ---------------- emb fp32 -> bf16 (one-shot, halves pool gather traffic)
__global__ void convert_emb(const float* __restrict__ in, unsigned short* __restrict__ out, int n8) {
  int i = blockIdx.x * blockDim.x + threadIdx.x;  // one short8 (8 elems) per thread
  if (i >= n8) return;
  float4 v0 = ((const float4*)in)[i * 2];
  float4 v1 = ((const float4*)in)[i * 2 + 1];
  short8 o;
  o[0] = (short)f2bf(v0.x); o[1] = (short)f2bf(v0.y); o[2] = (short)f2bf(v0.z); o[3] = (short)f2bf(v0.w);
  o[4] = (short)f2bf(v1.x); o[5] = (short)f2bf(v1.y); o[6] = (short)f2bf(v1.z); o[7] = (short)f2bf(v1.w);
  ((short8*)out)[i] = o;
}

// ---------------- transpose + fp32->bf16 convert:  in [E][R][C] f32 -> out [E][C][R] bf16
__global__ void transpose_bf16(const float* __restrict__ in, unsigned short* __restrict__ out,
                               int R, int C) {
  __shared__ float tile[32][33];
  int e = blockIdx.z;
  int c0 = blockIdx.x * 32, r0 = blockIdx.y * 32;
  const float* ip = in + (size_t)e * R * C;
  unsigned short* op = out + (size_t)e * R * C;
  int tx = threadIdx.x, ty = threadIdx.y;  // 32 x 8
  #pragma unroll
  for (int i = 0; i < 32; i += 8)
    tile[ty + i][tx] = ip[(size_t)(r0 + ty + i) * C + c0 + tx];
  __syncthreads();
  #pragma unroll
  for (int i = 0; i < 32; i += 8)
    op[(size_t)(c0 + ty + i) * R + r0 + tx] = f2bf(tile[tx][ty + i]);
}

// ---------------- fused mean-pool (bf16 gather) + gate matmul + softmax/argmax
// 128 threads = 2 waves = 2 tokens; each wave independent.
__global__ void pool_gate_kernel(const int* __restrict__ x, const unsigned short* __restrict__ embb,
                                 const float* __restrict__ wg, unsigned short* __restrict__ xmb,
                                 int* __restrict__ eidx, float* __restrict__ gate) {
  int tok = blockIdx.x * 2 + (threadIdx.x >> 6);
  int lane = threadIdx.x & 63;
  int xi = x[tok * SEQ + lane];  // one index per lane (SEQ==64)
  float a[8];
  #pragma unroll
  for (int j = 0; j < 8; j++) a[j] = 0.f;
  const short8* base = (const short8*)embb;  // row stride = 64 short8s
  #pragma unroll 8
  for (int s = 0; s < SEQ; s++) {
    int row = __shfl(xi, s);
    short8 v = base[(size_t)row * 64 + lane];
    #pragma unroll
    for (int j = 0; j < 8; j++) a[j] += bf2f((unsigned short)v[j]);
  }
  #pragma unroll
  for (int j = 0; j < 8; j++) a[j] *= (1.0f / 64.0f);
  // write bf16 pooled row (FFN input)
  short8 o;
  #pragma unroll
  for (int j = 0; j < 8; j++) o[j] = (short)f2bf(a[j]);
  *(short8*)(xmb + (size_t)tok * EMBD + lane * 8) = o;
  // gate partials: this lane owns columns lane*8..lane*8+7
  float p[16];
  #pragma unroll
  for (int e2 = 0; e2 < 16; e2++) p[e2] = 0.f;
  #pragma unroll
  for (int j = 0; j < 8; j++) {
    const float4* wr = (const float4*)(wg + (size_t)(lane * 8 + j) * NEXP);
    float4 q0 = wr[0], q1 = wr[1], q2 = wr[2], q3 = wr[3];
    p[0] += a[j] * q0.x; p[1] += a[j] * q0.y; p[2] += a[j] * q0.z; p[3] += a[j] * q0.w;
    p[4] += a[j] * q1.x; p[5] += a[j] * q1.y; p[6] += a[j] * q1.z; p[7] += a[j] * q1.w;
    p[8] += a[j] * q2.x; p[9] += a[j] * q2.y; p[10] += a[j] * q2.z; p[11] += a[j] * q2.w;
    p[12] += a[j] * q3.x; p[13] += a[j] * q3.y; p[14] += a[j] * q3.z; p[15] += a[j] * q3.w;
  }
  #pragma unroll
  for (int d = 1; d < 64; d <<= 1) {
    #pragma unroll
    for (int e2 = 0; e2 < 16; e2++) p[e2] += __shfl_xor(p[e2], d);
  }
  // first-max argmax + softmax prob of winner (all lanes redundant)
  float best = p[0]; int bi = 0;
  #pragma unroll
  for (int e2 = 1; e2 < 16; e2++) { if (p[e2] > best) { best = p[e2]; bi = e2; } }
  float ssum = 0.f;
  #pragma unroll
  for (int e2 = 0; e2 < 16; e2++) ssum += __expf(p[e2] - best);
  if (lane == 0) { eidx[tok] = bi; gate[tok] = 1.0f / ssum; }
}

// ---------------- slot assignment: sequential per-expert prefix count (order matters!)
__global__ void assign_kernel(const int* __restrict__ eidx, int* __restrict__ slot,
                              int* __restrict__ dest) {
  __shared__ int sidx[NTOK];
  int tid = threadIdx.x;  // 1024 = 16 waves
  for (int i = tid; i < NTOK; i += 1024) { sidx[i] = eidx[i]; dest[i] = 0; }
  __syncthreads();
  int e = tid >> 6;      // wave id == expert
  int lane = tid & 63;
  int run = 0;
  for (int c = 0; c < NTOK; c += 64) {
    int v = sidx[c + lane];
    unsigned long long m = __ballot(v == e);
    int before = __popcll(m & ((1ull << lane) - 1ull));
    if (v == e) {
      int sl = run + before;
      if (sl < CAPS) { slot[c + lane] = sl; dest[e * CAPS + sl] = c + lane; }
      else slot[c + lane] = -1;
    }
    run += __popcll(m);
  }
}

// ---------------- grouped GEMM (bf16 MFMA, 128x128 tile, 4 waves)
// m97-style: global_load_lds width=16, linear LDS dest, inverse-swizzled global
// source, XOR-swizzled ds_read (rule 21 / m201 pattern).
// C[m][n] = sum_k A[m][k] * BT[n][k] (+bias), expert e / K-split from blockIdx.z
template <int LDK, int NTOTL, int KSPLIT, bool GATHER, bool RELU_BF16>
__global__ __launch_bounds__(256) void gemm_moe(
    const unsigned short* __restrict__ A0, const int* __restrict__ dest,
    const unsigned short* __restrict__ BT, const float* __restrict__ bias,
    unsigned short* __restrict__ hout, float* __restrict__ yout) {
  __shared__ unsigned short Als[128 * 64];
  __shared__ unsigned short Bls[128 * 64];
  __shared__ int tokrow[128];

  const int e = blockIdx.z / KSPLIT;
  const int ksp = blockIdx.z % KSPLIT;
  const int kbase = ksp * (LDK / KSPLIT);  // element offset into K
  const int n0 = blockIdx.x * 128;
  const int m0 = blockIdx.y * 128;
  const int tid = threadIdx.x;
  const int lane = tid & 63;
  const int wv = tid >> 6;
  const int wr = (wv >> 1) * 64;
  const int wc = (wv & 1) * 64;
  const int l15 = lane & 15;
  const int lhi = lane >> 4;

  if (GATHER) {
    if (tid < 128) tokrow[tid] = dest[e * CAPS + m0 + tid];
  }
  __syncthreads();

  // staging: wave wv, issue i, lane l handles row r = i*32 + wv*8 + (l>>3),
  // 16B chunk c = l&7. LDS dest linear (HW scatters lane*16); global source
  // pre-swizzled so LDS[r][b] holds global[r][b ^ ((r&7)<<4)].
  const int r8 = lane >> 3, c8 = lane & 7;
  const char* asrc[4];
  const char* bsrc[4];
  char* adst[4];
  char* bdst[4];
  #pragma unroll
  for (int i = 0; i < 4; i++) {
    int row = i * 32 + wv * 8 + r8;
    int sw = (c8 * 16) ^ ((row & 7) << 4);
    size_t arow = GATHER ? (size_t)tokrow[row] : (size_t)(e * CAPS + m0 + row);
    asrc[i] = (const char*)(A0 + arow * LDK + kbase) + sw;
    bsrc[i] = (const char*)(BT + ((size_t)e * NTOTL + n0 + row) * LDK + kbase) + sw;
    adst[i] = (char*)Als + (size_t)(i * 32 + wv * 8) * 128;
    bdst[i] = (char*)Bls + (size_t)(i * 32 + wv * 8) * 128;
  }

  f32x4 acc[4][4];
  #pragma unroll
  for (int a = 0; a < 4; a++)
    #pragma unroll
    for (int b = 0; b < 4; b++) acc[a][b] = (f32x4){0.f, 0.f, 0.f, 0.f};

  const int NK = (LDK / KSPLIT) / 64;
  for (int kt = 0; kt < NK; kt++) {
    __syncthreads();  // previous compute done reading LDS
    #pragma unroll
    for (int i = 0; i < 4; i++) {
      __builtin_amdgcn_global_load_lds((as1_u32p)(const void*)(asrc[i] + kt * 128),
                                       (as3_u32p)(void*)adst[i], 16, 0, 0);
      __builtin_amdgcn_global_load_lds((as1_u32p)(const void*)(bsrc[i] + kt * 128),
                                       (as3_u32p)(void*)bdst[i], 16, 0, 0);
    }
    __syncthreads();  // compiler drains vmcnt(0) before barrier -> LDS ready
    #pragma unroll
    for (int ks = 0; ks < 2; ks++) {
      short8 af[4], bfr[4];
      #pragma unroll
      for (int mi = 0; mi < 4; mi++) {
        int row = wr + mi * 16 + l15;
        int off = row * 128 + (((ks * 32 + lhi * 8) * 2) ^ ((row & 7) << 4));
        af[mi] = *(const short8*)((const char*)Als + off);
      }
      #pragma unroll
      for (int ni = 0; ni < 4; ni++) {
        int row = wc + ni * 16 + l15;
        int off = row * 128 + (((ks * 32 + lhi * 8) * 2) ^ ((row & 7) << 4));
        bfr[ni] = *(const short8*)((const char*)Bls + off);
      }
      #pragma unroll
      for (int mi = 0; mi < 4; mi++)
        #pragma unroll
        for (int ni = 0; ni < 4; ni++)
          acc[mi][ni] = __builtin_amdgcn_mfma_f32_16x16x32_bf16(af[mi], bfr[ni], acc[mi][ni], 0, 0, 0);
    }
  }

  // epilogue: D row=(lane>>4)*4+j, col=lane&15 (m89-verified)
  float* yp = yout + (size_t)ksp * ((size_t)NEXP * CAPS * NTOTL);
  #pragma unroll
  for (int ni = 0; ni < 4; ni++) {
    int col = n0 + wc + ni * 16 + l15;
    float bs = RELU_BF16 ? bias[e * NTOTL + col] : 0.f;
    #pragma unroll
    for (int mi = 0; mi < 4; mi++) {
      f32x4 v = acc[mi][ni];
      #pragma unroll
      for (int j = 0; j < 4; j++) {
        int row = m0 + wr + mi * 16 + lhi * 4 + j;
        float xv = v[j] + bs;
        size_t oidx = ((size_t)(e * CAPS + row)) * NTOTL + col;
        if (RELU_BF16) hout[oidx] = f2bf(fmaxf(xv, 0.f));
        else           yp[oidx] = xv;
      }
    }
  }
}

// ---------------- combine split-K partials + b2 + final fc + log_softmax (one wave/token)
__global__ void combine_kernel(const float* __restrict__ ye0, const float* __restrict__ ye1,
                               const float* __restrict__ b2, const int* __restrict__ eidx,
                               const int* __restrict__ slot, const float* __restrict__ gate,
                               const float* __restrict__ fcw, const float* __restrict__ fcb,
                               float* __restrict__ out) {
  int b = blockIdx.x * 4 + (threadIdx.x >> 6);
  int lane = threadIdx.x & 63;
  int s = slot[b];
  float z0, z1;
  if (s >= 0) {
    int e = eidx[b];
    size_t off = ((size_t)(e * CAPS + s)) * EMBD;
    float a0 = 0, a1 = 0;
    #pragma unroll
    for (int i = 0; i < EMBD / 64; i++) {
      int c = lane + i * 64;
      float v = ye0[off + c] + ye1[off + c] + b2[e * EMBD + c];
      a0 += v * fcw[c * 2 + 0];
      a1 += v * fcw[c * 2 + 1];
    }
    #pragma unroll
    for (int d = 1; d < 64; d <<= 1) { a0 += __shfl_xor(a0, d); a1 += __shfl_xor(a1, d); }
    float g = gate[b];
    z0 = g * a0 + fcb[0];
    z1 = g * a1 + fcb[1];
  } else {
    z0 = fcb[0]; z1 = fcb[1];  // dropped token: y = 0
  }
  if (lane == 0) {
    float m = fmaxf(z0, z1);
    float lse = m + logf(expf(z0 - m) + expf(z1 - m));
    out[(size_t)b * 2 + 0] = z0 - lse;
    out[(size_t)b * 2 + 1] = z1 - lse;
  }
}

extern "C" void kernel_launch(void* const* d_in, const int* in_sizes, int n_in,
                              void* d_out, int out_size, void* d_ws, size_t ws_size,
                              hipStream_t stream) {
  const int* x = (const int*)d_in[0];
  const float* emb = (const float*)d_in[1];
  const float* wg = (const float*)d_in[2];
  const float* w1 = (const float*)d_in[3];
  const float* b1 = (const float*)d_in[4];
  const float* w2 = (const float*)d_in[5];
  const float* b2 = (const float*)d_in[6];
  const float* fcw = (const float*)d_in[7];
  const float* fcb = (const float*)d_in[8];
  float* out = (float*)d_out;

  // Workspace layout with lifetime overlays (peak ~127 MB):
  //   [0,32M)        w2T  (live: transpose .. gemm2)
  //   [32M,64M)      w1T  (live: transpose .. gemm1) -> ye0/ye1 (gemm2 .. combine)
  //   [64M,~115.2M)  embb (live: convert .. pool_gate) -> h at [64M,96M) (gemm1 .. gemm2)
  //   [~115.2M, ..)  xmb, eidx, gate, slot, dest
  char* ws = (char*)d_ws;
  unsigned short* w2T = (unsigned short*)(ws + 0);
  unsigned short* w1T = (unsigned short*)(ws + 33554432);
  float* ye0          = (float*)(ws + 33554432);        // overlays w1T after gemm1
  float* ye1          = ye0 + (size_t)NEXP * CAPS * EMBD;
  unsigned short* embb= (unsigned short*)(ws + 67108864);
  unsigned short* h   = (unsigned short*)(ws + 67108864); // overlays embb after pool_gate
  unsigned short* xmb = (unsigned short*)(ws + 118308864);
  int* eidx           = (int*)(ws + 126697472);
  float* gate         = (float*)(ws + 126730240);
  int* slot           = (int*)(ws + 126763008);
  int* dest           = (int*)(ws + 126795776);

  convert_emb<<<12500, 256, 0, stream>>>(emb, embb, (50000 * EMBD) / 8);
  transpose_bf16<<<dim3(FFND / 32, EMBD / 32, NEXP), dim3(32, 8), 0, stream>>>(w1, w1T, EMBD, FFND);
  transpose_bf16<<<dim3(EMBD / 32, FFND / 32, NEXP), dim3(32, 8), 0, stream>>>(w2, w2T, FFND, EMBD);
  pool_gate_kernel<<<NTOK / 2, 128, 0, stream>>>(x, embb, wg, xmb, eidx, gate);
  assign_kernel<<<1, 1024, 0, stream>>>(eidx, slot, dest);
  // FFN1: [CAP x 512] @ [512 x 2048] -> relu -> h (bf16)
  gemm_moe<EMBD, FFND, 1, true, true><<<dim3(FFND / 128, CAPS / 128, NEXP), 256, 0, stream>>>(
      xmb, dest, w1T, b1, h, nullptr);
  // FFN2: [CAP x 2048] @ [2048 x 512], split-K=2 -> ye0/ye1 (fp32 partials)
  gemm_moe<FFND, EMBD, 2, false, false><<<dim3(EMBD / 128, CAPS / 128, NEXP * 2), 256, 0, stream>>>(
      h, nullptr, w2T, nullptr, nullptr, ye0);
  combine_kernel<<<NTOK / 4, 256, 0, stream>>>(ye0, ye1, b2, eidx, slot, gate, fcw, fcb, out);
}

// Round 8
// 427.195 us; speedup vs baseline: 1.5440x; 1.0783x over previous
//
#include <hip/hip_runtime.h>
#include <hip/hip_bf16.h>

// Problem constants
#define NTOK 8192
#define SEQ 64
#define EMBD 512
#define NEXP 16
#define FFND 2048
#define CAPS 512
#define VOCABSZ 3200000  // 50000*512/8 short8 units

typedef __attribute__((ext_vector_type(8))) short short8;
typedef __attribute__((ext_vector_type(4))) float f32x4;

typedef const __attribute__((address_space(1))) unsigned int* as1_u32p;
typedef __attribute__((address_space(3))) unsigned int* as3_u32p;

__device__ __forceinline__ unsigned short f2bf(float f) {
  union { float f; unsigned u; } a; a.f = f;
  unsigned r = (a.u + 0x7fff + ((a.u >> 16) & 1)) >> 16;  // RNE
  return (unsigned short)r;
}
__device__ __forceinline__ float bf2f(unsigned short h) {
  union { unsigned u; float f; } a; a.u = ((unsigned)h) << 16; return a.f;
}

// ---------------- fused preprocess: emb fp32->bf16 convert + w1/w2 transpose+convert
// grid (32, 8, 96): z<16 -> w1 expert z; z<32 -> w2 expert z-16; else emb chunk.
__global__ __launch_bounds__(256) void preprocess_kernel(
    const float* __restrict__ emb, const float* __restrict__ w1, const float* __restrict__ w2,
    unsigned short* __restrict__ embb, unsigned short* __restrict__ w1T,
    unsigned short* __restrict__ w2T) {
  const int z = blockIdx.z;
  const int tid = threadIdx.x;
  if (z >= 32) {
    // emb convert: one short8 (8 elems) per thread-iteration
    const int n8 = VOCABSZ;
    int i = ((z - 32) * 256 + (int)(blockIdx.y * 32 + blockIdx.x)) * 256 + tid;
    if (i < n8) {
      float4 v0 = ((const float4*)emb)[i * 2];
      float4 v1 = ((const float4*)emb)[i * 2 + 1];
      short8 o;
      o[0] = (short)f2bf(v0.x); o[1] = (short)f2bf(v0.y); o[2] = (short)f2bf(v0.z); o[3] = (short)f2bf(v0.w);
      o[4] = (short)f2bf(v1.x); o[5] = (short)f2bf(v1.y); o[6] = (short)f2bf(v1.z); o[7] = (short)f2bf(v1.w);
      ((short8*)embb)[i] = o;
    }
    return;
  }
  // 64x64 transpose tile: in [R][C] f32 -> out [C][R] bf16
  __shared__ float tile[64][65];
  const float* ip; unsigned short* op; int R, C, r0, c0;
  if (z < 16) {  // w1: [512][2048] per expert
    R = EMBD; C = FFND;
    ip = w1 + (size_t)z * R * C; op = w1T + (size_t)z * R * C;
    c0 = blockIdx.x * 64; r0 = blockIdx.y * 64;
  } else {       // w2: [2048][512] per expert
    R = FFND; C = EMBD;
    ip = w2 + (size_t)(z - 16) * R * C; op = w2T + (size_t)(z - 16) * R * C;
    r0 = blockIdx.x * 64; c0 = blockIdx.y * 64;
  }
  #pragma unroll
  for (int p = 0; p < 4; p++) {
    int r = p * 16 + (tid >> 4), cg = (tid & 15) * 4;
    float4 v = *(const float4*)(ip + (size_t)(r0 + r) * C + c0 + cg);
    tile[r][cg + 0] = v.x; tile[r][cg + 1] = v.y; tile[r][cg + 2] = v.z; tile[r][cg + 3] = v.w;
  }
  __syncthreads();
  #pragma unroll
  for (int q = 0; q < 2; q++) {
    int c = q * 32 + (tid >> 3), rch = (tid & 7) * 8;
    short8 o;
    #pragma unroll
    for (int i = 0; i < 8; i++) o[i] = (short)f2bf(tile[rch + i][c]);
    *(short8*)(op + (size_t)(c0 + c) * R + r0 + rch) = o;
  }
}

// ---------------- pool (4 waves/token, 16 gathers in flight/lane) + gate + softmax/argmax
__global__ __launch_bounds__(256) void pool_gate_kernel(
    const int* __restrict__ x, const unsigned short* __restrict__ embb,
    const float* __restrict__ wg, unsigned short* __restrict__ xmb,
    int* __restrict__ eidx, float* __restrict__ gate) {
  __shared__ float part[4][EMBD];  // 8 KB
  __shared__ float xs[EMBD];       // 2 KB
  const int tok = blockIdx.x;
  const int tid = threadIdx.x;
  const int w = tid >> 6, lane = tid & 63;
  int xi = 0;
  if (lane < 16) xi = x[tok * SEQ + w * 16 + lane];
  const short8* base = (const short8*)embb;  // emb row = 64 short8s
  short8 vv[16];
  #pragma unroll
  for (int s = 0; s < 16; s++) {
    int row = __shfl(xi, s);
    vv[s] = base[(size_t)row * 64 + lane];
  }
  float a[8];
  #pragma unroll
  for (int j = 0; j < 8; j++) a[j] = 0.f;
  #pragma unroll
  for (int s = 0; s < 16; s++)
    #pragma unroll
    for (int j = 0; j < 8; j++) a[j] += bf2f((unsigned short)vv[s][j]);
  *(f32x4*)&part[w][lane * 8]     = (f32x4){a[0], a[1], a[2], a[3]};
  *(f32x4*)&part[w][lane * 8 + 4] = (f32x4){a[4], a[5], a[6], a[7]};
  __syncthreads();
  // reduce 4 partials, scale, emit bf16 row + fp32 row (for gate)
  {
    int c = tid * 2;
    float s0 = (part[0][c] + part[1][c] + part[2][c] + part[3][c]) * (1.f / 64.f);
    float s1 = (part[0][c + 1] + part[1][c + 1] + part[2][c + 1] + part[3][c + 1]) * (1.f / 64.f);
    xs[c] = s0; xs[c + 1] = s1;
    ((unsigned*)xmb)[tok * 256 + tid] = ((unsigned)f2bf(s1) << 16) | f2bf(s0);
  }
  __syncthreads();
  if (w != 0) return;
  // gate: lane owns cols lane*8..+7 of xs
  float g[8];
  {
    float4 v0 = *(const float4*)&xs[lane * 8];
    float4 v1 = *(const float4*)&xs[lane * 8 + 4];
    g[0] = v0.x; g[1] = v0.y; g[2] = v0.z; g[3] = v0.w;
    g[4] = v1.x; g[5] = v1.y; g[6] = v1.z; g[7] = v1.w;
  }
  float p[16];
  #pragma unroll
  for (int e2 = 0; e2 < 16; e2++) p[e2] = 0.f;
  #pragma unroll
  for (int j = 0; j < 8; j++) {
    const float4* wr = (const float4*)(wg + (size_t)(lane * 8 + j) * NEXP);
    float4 q0 = wr[0], q1 = wr[1], q2 = wr[2], q3 = wr[3];
    p[0] += g[j] * q0.x; p[1] += g[j] * q0.y; p[2]  += g[j] * q0.z; p[3]  += g[j] * q0.w;
    p[4] += g[j] * q1.x; p[5] += g[j] * q1.y; p[6]  += g[j] * q1.z; p[7]  += g[j] * q1.w;
    p[8] += g[j] * q2.x; p[9] += g[j] * q2.y; p[10] += g[j] * q2.z; p[11] += g[j] * q2.w;
    p[12] += g[j] * q3.x; p[13] += g[j] * q3.y; p[14] += g[j] * q3.z; p[15] += g[j] * q3.w;
  }
  #pragma unroll
  for (int d = 1; d < 64; d <<= 1) {
    #pragma unroll
    for (int e2 = 0; e2 < 16; e2++) p[e2] += __shfl_xor(p[e2], d);
  }
  float best = p[0]; int bi = 0;
  #pragma unroll
  for (int e2 = 1; e2 < 16; e2++) { if (p[e2] > best) { best = p[e2]; bi = e2; } }
  float ssum = 0.f;
  #pragma unroll
  for (int e2 = 0; e2 < 16; e2++) ssum += __expf(p[e2] - best);
  if (lane == 0) { eidx[tok] = bi; gate[tok] = 1.0f / ssum; }
}

// ---------------- slot assignment: sequential per-expert prefix count (order matters!)
__global__ void assign_kernel(const int* __restrict__ eidx, int* __restrict__ slot,
                              int* __restrict__ dest) {
  __shared__ int sidx[NTOK];
  int tid = threadIdx.x;  // 1024 = 16 waves
  for (int i = tid; i < NTOK; i += 1024) { sidx[i] = eidx[i]; dest[i] = 0; }
  __syncthreads();
  int e = tid >> 6;      // wave id == expert
  int lane = tid & 63;
  int run = 0;
  for (int c = 0; c < NTOK; c += 64) {
    int v = sidx[c + lane];
    unsigned long long m = __ballot(v == e);
    int before = __popcll(m & ((1ull << lane) - 1ull));
    if (v == e) {
      int sl = run + before;
      if (sl < CAPS) { slot[c + lane] = sl; dest[e * CAPS + sl] = c + lane; }
      else slot[c + lane] = -1;
    }
    run += __popcll(m);
  }
}

// ---------------- grouped GEMM (bf16 MFMA, 128x128 tile, 4 waves)
// m97-style: global_load_lds width=16, linear LDS dest, inverse-swizzled global
// source, XOR-swizzled ds_read (rule 21 / m201 pattern). Output always bf16.
template <int LDK, int NTOTL, int KSPLIT, bool GATHER, bool RELU_BIAS>
__global__ __launch_bounds__(256) void gemm_moe(
    const unsigned short* __restrict__ A0, const int* __restrict__ dest,
    const unsigned short* __restrict__ BT, const float* __restrict__ bias,
    unsigned short* __restrict__ hout) {
  __shared__ unsigned short Als[128 * 64];
  __shared__ unsigned short Bls[128 * 64];
  __shared__ int tokrow[128];

  const int e = blockIdx.z / KSPLIT;
  const int ksp = blockIdx.z % KSPLIT;
  const int kbase = ksp * (LDK / KSPLIT);
  const int n0 = blockIdx.x * 128;
  const int m0 = blockIdx.y * 128;
  const int tid = threadIdx.x;
  const int lane = tid & 63;
  const int wv = tid >> 6;
  const int wr = (wv >> 1) * 64;
  const int wc = (wv & 1) * 64;
  const int l15 = lane & 15;
  const int lhi = lane >> 4;

  if (GATHER) {
    if (tid < 128) tokrow[tid] = dest[e * CAPS + m0 + tid];
  }
  __syncthreads();

  const int r8 = lane >> 3, c8 = lane & 7;
  const char* asrc[4];
  const char* bsrc[4];
  char* adst[4];
  char* bdst[4];
  #pragma unroll
  for (int i = 0; i < 4; i++) {
    int row = i * 32 + wv * 8 + r8;
    int sw = (c8 * 16) ^ ((row & 7) << 4);
    size_t arow = GATHER ? (size_t)tokrow[row] : (size_t)(e * CAPS + m0 + row);
    asrc[i] = (const char*)(A0 + arow * LDK + kbase) + sw;
    bsrc[i] = (const char*)(BT + ((size_t)e * NTOTL + n0 + row) * LDK + kbase) + sw;
    adst[i] = (char*)Als + (size_t)(i * 32 + wv * 8) * 128;
    bdst[i] = (char*)Bls + (size_t)(i * 32 + wv * 8) * 128;
  }

  f32x4 acc[4][4];
  #pragma unroll
  for (int a = 0; a < 4; a++)
    #pragma unroll
    for (int b = 0; b < 4; b++) acc[a][b] = (f32x4){0.f, 0.f, 0.f, 0.f};

  const int NK = (LDK / KSPLIT) / 64;
  for (int kt = 0; kt < NK; kt++) {
    __syncthreads();
    #pragma unroll
    for (int i = 0; i < 4; i++) {
      __builtin_amdgcn_global_load_lds((as1_u32p)(const void*)(asrc[i] + kt * 128),
                                       (as3_u32p)(void*)adst[i], 16, 0, 0);
      __builtin_amdgcn_global_load_lds((as1_u32p)(const void*)(bsrc[i] + kt * 128),
                                       (as3_u32p)(void*)bdst[i], 16, 0, 0);
    }
    __syncthreads();
    #pragma unroll
    for (int ks = 0; ks < 2; ks++) {
      short8 af[4], bfr[4];
      #pragma unroll
      for (int mi = 0; mi < 4; mi++) {
        int row = wr + mi * 16 + l15;
        int off = row * 128 + (((ks * 32 + lhi * 8) * 2) ^ ((row & 7) << 4));
        af[mi] = *(const short8*)((const char*)Als + off);
      }
      #pragma unroll
      for (int ni = 0; ni < 4; ni++) {
        int row = wc + ni * 16 + l15;
        int off = row * 128 + (((ks * 32 + lhi * 8) * 2) ^ ((row & 7) << 4));
        bfr[ni] = *(const short8*)((const char*)Bls + off);
      }
      #pragma unroll
      for (int mi = 0; mi < 4; mi++)
        #pragma unroll
        for (int ni = 0; ni < 4; ni++)
          acc[mi][ni] = __builtin_amdgcn_mfma_f32_16x16x32_bf16(af[mi], bfr[ni], acc[mi][ni], 0, 0, 0);
    }
  }

  // epilogue: D row=(lane>>4)*4+j, col=lane&15 (m89-verified)
  unsigned short* hp = hout + (size_t)ksp * ((size_t)NEXP * CAPS * NTOTL);
  #pragma unroll
  for (int ni = 0; ni < 4; ni++) {
    int col = n0 + wc + ni * 16 + l15;
    float bs = RELU_BIAS ? bias[e * NTOTL + col] : 0.f;
    #pragma unroll
    for (int mi = 0; mi < 4; mi++) {
      f32x4 v = acc[mi][ni];
      #pragma unroll
      for (int j = 0; j < 4; j++) {
        int row = m0 + wr + mi * 16 + lhi * 4 + j;
        float xv = v[j] + bs;
        size_t oidx = ((size_t)(e * CAPS + row)) * NTOTL + col;
        hp[oidx] = f2bf(RELU_BIAS ? fmaxf(xv, 0.f) : xv);
      }
    }
  }
}

// ---------------- combine bf16 split-K partials + b2 + final fc + log_softmax
__global__ void combine_kernel(const unsigned short* __restrict__ ye0,
                               const unsigned short* __restrict__ ye1,
                               const float* __restrict__ b2, const int* __restrict__ eidx,
                               const int* __restrict__ slot, const float* __restrict__ gate,
                               const float* __restrict__ fcw, const float* __restrict__ fcb,
                               float* __restrict__ out) {
  int b = blockIdx.x * 4 + (threadIdx.x >> 6);
  int lane = threadIdx.x & 63;
  int s = slot[b];
  float z0, z1;
  if (s >= 0) {
    int e = eidx[b];
    size_t off = ((size_t)(e * CAPS + s)) * EMBD + lane * 8;
    short8 v0 = *(const short8*)(ye0 + off);
    short8 v1 = *(const short8*)(ye1 + off);
    const float4* bb = (const float4*)(b2 + e * EMBD + lane * 8);
    float4 b20 = bb[0], b21 = bb[1];
    float bv[8] = {b20.x, b20.y, b20.z, b20.w, b21.x, b21.y, b21.z, b21.w};
    const float4* fw = (const float4*)(fcw + lane * 16);
    float a0 = 0, a1 = 0;
    #pragma unroll
    for (int j = 0; j < 8; j++) {
      float v = bf2f((unsigned short)v0[j]) + bf2f((unsigned short)v1[j]) + bv[j];
      float4 q = fw[j >> 1];
      float w0 = (j & 1) ? q.z : q.x;
      float w1 = (j & 1) ? q.w : q.y;
      a0 += v * w0; a1 += v * w1;
    }
    #pragma unroll
    for (int d = 1; d < 64; d <<= 1) { a0 += __shfl_xor(a0, d); a1 += __shfl_xor(a1, d); }
    float g = gate[b];
    z0 = g * a0 + fcb[0];
    z1 = g * a1 + fcb[1];
  } else {
    z0 = fcb[0]; z1 = fcb[1];  // dropped token: y = 0
  }
  if (lane == 0) {
    float m = fmaxf(z0, z1);
    float lse = m + logf(expf(z0 - m) + expf(z1 - m));
    out[(size_t)b * 2 + 0] = z0 - lse;
    out[(size_t)b * 2 + 1] = z1 - lse;
  }
}

extern "C" void kernel_launch(void* const* d_in, const int* in_sizes, int n_in,
                              void* d_out, int out_size, void* d_ws, size_t ws_size,
                              hipStream_t stream) {
  const int* x = (const int*)d_in[0];
  const float* emb = (const float*)d_in[1];
  const float* wg = (const float*)d_in[2];
  const float* w1 = (const float*)d_in[3];
  const float* b1 = (const float*)d_in[4];
  const float* w2 = (const float*)d_in[5];
  const float* b2 = (const float*)d_in[6];
  const float* fcw = (const float*)d_in[7];
  const float* fcb = (const float*)d_in[8];
  float* out = (float*)d_out;

  // Workspace overlays (peak ~125 MB):
  //  [0,32M)    w2T (transpose..gemm2)
  //  [32M,64M)  w1T (transpose..gemm1) -> ye0/ye1 bf16 8MB+8MB (gemm2..combine)
  //  [64M,~115M) embb (convert..pool) -> h 32MB (gemm1..gemm2)
  //  [116M,..)  xmb, eidx, gate, slot, dest
  char* ws = (char*)d_ws;
  unsigned short* w2T = (unsigned short*)(ws + 0);
  unsigned short* w1T = (unsigned short*)(ws + 33554432);
  unsigned short* ye0 = (unsigned short*)(ws + 33554432);   // overlays w1T after gemm1
  unsigned short* ye1 = ye0 + (size_t)NEXP * CAPS * EMBD;
  unsigned short* embb= (unsigned short*)(ws + 67108864);
  unsigned short* h   = (unsigned short*)(ws + 67108864);   // overlays embb after pool
  unsigned short* xmb = (unsigned short*)(ws + 121634816);
  int* eidx           = (int*)(ws + 130023424);
  float* gate         = (float*)(ws + 130056192);
  int* slot           = (int*)(ws + 130088960);
  int* dest           = (int*)(ws + 130121728);

  preprocess_kernel<<<dim3(32, 8, 96), 256, 0, stream>>>(emb, w1, w2, embb, w1T, w2T);
  pool_gate_kernel<<<NTOK, 256, 0, stream>>>(x, embb, wg, xmb, eidx, gate);
  assign_kernel<<<1, 1024, 0, stream>>>(eidx, slot, dest);
  // FFN1: [CAP x 512] @ [512 x 2048] -> relu -> h (bf16)
  gemm_moe<EMBD, FFND, 1, true, true><<<dim3(FFND / 128, CAPS / 128, NEXP), 256, 0, stream>>>(
      xmb, dest, w1T, b1, h);
  // FFN2: [CAP x 2048] @ [2048 x 512], split-K=2 -> ye0/ye1 (bf16 partials)
  gemm_moe<FFND, EMBD, 2, false, false><<<dim3(EMBD / 128, CAPS / 128, NEXP * 2), 256, 0, stream>>>(
      h, nullptr, w2T, nullptr, ye0);
  combine_kernel<<<NTOK / 4, 256, 0, stream>>>(ye0, ye1, b2, eidx, slot, gate, fcw, fcb, out);
}